// Round 11
// baseline (217.289 us; speedup 1.0000x reference)
//
#include <hip/hip_runtime.h>
#include <hip/hip_bf16.h>

// MultiHeadSelfAttention: B=2, S=2048, D=1024, H=16, DK=64
// R17: fuse attn + out-GEMM into ONE dispatch. Budget closure showed ~35µs of
//      dispatch gaps (5 boundaries x ~7µs, calibrated by R12) + 42µs harness
//      poison-fill; gaps are the largest addressable item. out-GEMM's TM=64
//      form has EXACTLY attn's geometry (512 blocks x 256 thr) so the attn
//      body is unchanged (no phase-locking risk). Software grid barrier:
//      512 blocks x 66.5KB/128VGPR = 2 blocks/CU co-resident (no deadlock);
//      counter zeroed by prep (3 dispatches upstream, no extra memset gap);
//      threadfence release/acquire handles XCD L2 non-coherence (G16).

using bf16 = __hip_bfloat16;
typedef __attribute__((ext_vector_type(8))) short bf16x8;   // 8 bf16 = 4 VGPRs
typedef __attribute__((ext_vector_type(4))) float f32x4;

#define QSCALE 0.18033688011112042f   // (1/sqrt(64)) * log2(e)

static __device__ __forceinline__ f32x4 mfma_bf16(bf16x8 a, bf16x8 b, f32x4 c) {
    return __builtin_amdgcn_mfma_f32_16x16x32_bf16(a, b, c, 0, 0, 0);
}

static __device__ __forceinline__ void gld_lds16(const void* g, void* s) {
    __builtin_amdgcn_global_load_lds(
        (const __attribute__((address_space(1))) unsigned int*)g,
        (__attribute__((address_space(3))) unsigned int*)s,
        16, 0, 0);
}

static __device__ __forceinline__ short f2s(float f) {
    bf16 h = __float2bfloat16(f);
    return *reinterpret_cast<short*>(&h);
}

// single-use software grid barrier (counter pre-zeroed by prep_kernel).
// release/acquire fences publish/invalidate across non-coherent XCD L2s.
static __device__ __forceinline__ void grid_sync(unsigned* bar, unsigned nblk) {
    __syncthreads();
    if (threadIdx.x == 0) {
        __threadfence();                       // release: publish this block's stores
        atomicAdd(bar, 1u);
        while (atomicAdd(bar, 0u) < nblk) __builtin_amdgcn_s_sleep(2);
        __threadfence();                       // acquire: see other blocks' stores
    }
    __syncthreads();
}

// ---------------- fused prep: cast x + transpose both weights + barrier init ----------------
__global__ void prep_kernel(const float* __restrict__ x, bf16* __restrict__ xb,
                            const float* __restrict__ wqkv, bf16* __restrict__ wqkvT,
                            const float* __restrict__ wo, bf16* __restrict__ woT,
                            unsigned* __restrict__ bar) {
    __shared__ float tile[32][33];
    int blk = blockIdx.x;
    if (blk == 0 && threadIdx.x == 0) atomicExch(bar, 0u);   // init grid barrier
    if (blk < 4096) {
        int i = blk * 256 + threadIdx.x;
        float4 f = reinterpret_cast<const float4*>(x)[i];
        xb[4*i+0] = __float2bfloat16(f.x);
        xb[4*i+1] = __float2bfloat16(f.y);
        xb[4*i+2] = __float2bfloat16(f.z);
        xb[4*i+3] = __float2bfloat16(f.w);
        return;
    }
    const float* in; bf16* out; int R, C, bx, by;
    if (blk < 7168) {
        int idx = blk - 4096; in = wqkv; out = wqkvT; R = 1024; C = 3072;
        bx = idx % 96; by = idx / 96;
    } else {
        int idx = blk - 7168; in = wo; out = woT; R = 1024; C = 1024;
        bx = idx & 31; by = idx >> 5;
    }
    int c0 = bx * 32, r0 = by * 32;
    int xo = threadIdx.x & 31, yo = threadIdx.x >> 5;   // (32,8)
#pragma unroll
    for (int i = 0; i < 32; i += 8) tile[yo + i][xo] = in[(size_t)(r0 + yo + i) * C + c0 + xo];
    __syncthreads();
#pragma unroll
    for (int i = 0; i < 32; i += 8)
        out[(size_t)(c0 + yo + i) * R + r0 + xo] = __float2bfloat16(tile[xo][yo + i]);
}

// ---------------- QKV GEMM: C[M,N] = A[M,K] @ Bt[N,K]^T  (bf16 in, fp32 acc) ----------------
template <int TM, int MINW>
__global__ __launch_bounds__(256, MINW)
void gemm_bt_kernel(const bf16* __restrict__ A, const bf16* __restrict__ Bt,
                    int M, int N, int K,
                    const float* __restrict__ bias,
                    bf16* __restrict__ Qout, bf16* __restrict__ Kout, bf16* __restrict__ Vout) {
    constexpr int MI = TM / 32;
    constexpr int CA = TM / 32;
    __shared__ __align__(16) bf16 As[TM * 64];
    __shared__ __align__(16) bf16 Bs[128 * 64];

    const int tid  = threadIdx.x;
    const int wave = tid >> 6, lane = tid & 63;
    const int quad = lane >> 4, l16 = lane & 15;
    const int wr = wave >> 1, wc = wave & 1;
    const int bm = blockIdx.y, bn = blockIdx.x;

    f32x4 acc[MI][4] = {};

    const int crow = lane >> 3;
    const int sblk = (lane & 7) ^ (crow & 7);
    const bf16* gA[CA]; const bf16* gB[4]; bf16* lA[CA]; bf16* lB[4];
#pragma unroll
    for (int c = 0; c < CA; ++c) {
        int ch = wave * CA + c;
        gA[c] = A + (size_t)(bm * TM + ch * 8 + crow) * K + sblk * 8;
        lA[c] = As + ch * 512 + lane * 8;
    }
#pragma unroll
    for (int c = 0; c < 4; ++c) {
        int ch = wave * 4 + c;
        gB[c] = Bt + (size_t)(bn * 128 + ch * 8 + crow) * K + sblk * 8;
        lB[c] = Bs + ch * 512 + lane * 8;
    }
    const int xr = l16 & 7;

    for (int k0 = 0; k0 < K; k0 += 64) {
#pragma unroll
        for (int c = 0; c < CA; ++c) gld_lds16(gA[c] + k0, lA[c]);
#pragma unroll
        for (int c = 0; c < 4; ++c) gld_lds16(gB[c] + k0, lB[c]);
        __syncthreads();
#pragma unroll
        for (int ks = 0; ks < 2; ++ks) {
            bf16x8 af[MI], bfr[4];
#pragma unroll
            for (int mi = 0; mi < MI; ++mi)
                af[mi] = *(const bf16x8*)(As + (wr * (TM/2) + mi * 16 + l16) * 64 + ((4 * ks + quad) ^ xr) * 8);
#pragma unroll
            for (int ni = 0; ni < 4; ++ni)
                bfr[ni] = *(const bf16x8*)(Bs + (wc * 64 + ni * 16 + l16) * 64 + ((4 * ks + quad) ^ xr) * 8);
#pragma unroll
            for (int mi = 0; mi < MI; ++mi)
#pragma unroll
                for (int ni = 0; ni < 4; ++ni)
                    acc[mi][ni] = mfma_bf16(af[mi], bfr[ni], acc[mi][ni]);
        }
        __syncthreads();
    }

#pragma unroll
    for (int mi = 0; mi < MI; ++mi) {
#pragma unroll
        for (int ni = 0; ni < 4; ++ni) {
            const int col = bn * 128 + wc * 64 + ni * 16 + l16;
            const int row0 = bm * TM + wr * (TM/2) + mi * 16 + quad * 4;
            const float bs = bias[col];
            float vv[4];
#pragma unroll
            for (int r = 0; r < 4; ++r) vv[r] = acc[mi][ni][r] + bs;
            const int h = col / 192;
            const int rr = col - h * 192;
            const int which = rr >> 6, dk = rr & 63;
            const int b = row0 >> 11, s0 = row0 & 2047;   // S = 2048
            const size_t bh = (size_t)b * 16 + h;
            if (which == 0) {
#pragma unroll
                for (int r = 0; r < 4; ++r)
                    Qout[(bh * 2048 + s0 + r) * 64 + dk] = __float2bfloat16(vv[r] * QSCALE);
            } else if (which == 1) {
#pragma unroll
                for (int r = 0; r < 4; ++r)
                    Kout[(bh * 2048 + s0 + r) * 64 + dk] = __float2bfloat16(vv[r]);
            } else {
                // V^T with kpos permutation (replaces transpose_v kernel):
                // s' = (s&~31) | ((s&12)<<1) | ((s&16)>>2) | (s&3); s0&3==0 so
                // the 4 r-values land at consecutive s' -> one short4 store.
                const int sp0 = (s0 & ~31) | ((s0 & 12) << 1) | ((s0 & 16) >> 2);
                short4 pv;
                pv.x = f2s(vv[0]); pv.y = f2s(vv[1]);
                pv.z = f2s(vv[2]); pv.w = f2s(vv[3]);
                *reinterpret_cast<short4*>(&Vout[(bh * 64 + dk) * 2048 + sp0]) = pv;
            }
        }
    }
}

// ---------------- fused attn (R14, unchanged body) + grid barrier + out-GEMM (TM=64) ----------------
// grid (16,32) = 512 blocks x 256 threads, 2 blocks/CU co-resident.
__global__ __launch_bounds__(256, 2)
void attn_out_kernel(const bf16* __restrict__ Qb, const bf16* __restrict__ Kb,
                     const bf16* __restrict__ Vtp, const int* __restrict__ mask,
                     bf16* __restrict__ Aout,
                     const bf16* __restrict__ WoT, const float* __restrict__ bo,
                     const float* __restrict__ gamma, float* __restrict__ Cout,
                     unsigned* __restrict__ bar) {
    __shared__ __align__(16) bf16 Ks[2][2][4096];   // [pair][tile][kpos*64+dk], XOR-swizzled
    __shared__ __align__(16) bf16 Vs[2][2][4096];   // [pair][tile][dk*64+kpos'], XOR-swizzled
    __shared__ float Biass[2][2][64];

    const int lid = blockIdx.x + (blockIdx.y << 4);
    const int tid = threadIdx.x;
    const int wave = tid >> 6, lane = tid & 63;
    const int quad = lane >> 4, l16 = lane & 15;
    const int xr = l16 & 7;

    // ================= stage 1: attention (R14 body, verified 42.0µs) =================
    {
        const int w   = (lid & 7) * 64 + (lid >> 3);
        const int bh  = w >> 4;
        const int b = bh >> 4, h = bh & 15;
        const int q0 = (w & 15) * 128;
        const int qg = (wave >> 1) & 1, kg = wave & 1;

        // Q fragments: wave owns q rows q0 + qg*64 + m*16 + l16  (m = 0..3)
        bf16x8 aq[4][2];
#pragma unroll
        for (int m = 0; m < 4; ++m) {
            const bf16* qp = Qb + ((size_t)bh * 2048 + q0 + qg * 64 + m * 16 + l16) * 64;
            aq[m][0] = *(const bf16x8*)(qp + quad * 8);
            aq[m][1] = *(const bf16x8*)(qp + 32 + quad * 8);
        }

        bf16x8 ones;
#pragma unroll
        for (int j = 0; j < 8; ++j) ones[j] = (short)0x3F80;   // bf16 1.0

        f32x4 O[4][4] = {};
        f32x4 Lacc[4] = {};

        const int r8 = lane >> 3, b8 = lane & 7;
        const int srcb = b8 ^ r8;
        const bf16* gK = Kb  + ((size_t)bh * 2048 + wave * 8 + r8) * 64 + srcb * 8;
        const bf16* gV = Vtp + ((size_t)bh * 64 + wave * 8 + r8) * 2048 + srcb * 8;
        const int so = wave * 512 + lane * 8;

        // prologue: tiles 0,1 -> pair0; bias tiles 0,1; mask prefetch tiles 2,3
        int mreg = 0;
#pragma unroll
        for (int ti = 0; ti < 2; ++ti)
#pragma unroll
            for (int c = 0; c < 2; ++c) {
                gld_lds16(gK + (size_t)ti * 4096 + c * 2048, &Ks[0][ti][c * 2048 + so]);
                gld_lds16(gV + (size_t)ti * 64 + c * 65536, &Vs[0][ti][c * 2048 + so]);
            }
        if (tid < 128) {
            Biass[0][tid >> 6][tid & 63] = mask[b * 2048 + tid] ? -24.0f : -1e30f;
            mreg = mask[b * 2048 + 128 + tid];
        }

        for (int t = 0; t < 16; ++t) {
            __syncthreads();   // pair[cur] DMA + bias landed; prior reads of pair[nxt] done
            const int cur = t & 1, nxt = cur ^ 1;

            if (t < 15) {
                const int u0 = 2 * t + 2;
#pragma unroll
                for (int ti = 0; ti < 2; ++ti)
#pragma unroll
                    for (int c = 0; c < 2; ++c) {
                        gld_lds16(gK + (size_t)(u0 + ti) * 4096 + c * 2048, &Ks[nxt][ti][c * 2048 + so]);
                        gld_lds16(gV + (size_t)(u0 + ti) * 64 + c * 65536, &Vs[nxt][ti][c * 2048 + so]);
                    }
                if (tid < 128) Biass[nxt][tid >> 6][tid & 63] = mreg ? -24.0f : -1e30f;
            }
            if (t < 14 && tid < 128) mreg = mask[b * 2048 + t * 128 + 256 + tid];

            // this wave's tile = 2t + kg: hoisted fragments (shared across 4 m-groups)
            const bf16* kb = &Ks[cur][kg][0];
            const bf16* vb = &Vs[cur][kg][0];
            f32x4 bias4[4];
            bf16x8 bk[4][2];
#pragma unroll
            for (int kt4 = 0; kt4 < 4; ++kt4) {
                bias4[kt4] = *(const f32x4*)(&Biass[cur][kg][0] + kt4 * 16 + quad * 4);
                const bf16* kp2 = kb + (kt4 * 16 + l16) * 64;
                bk[kt4][0] = *(const bf16x8*)(kp2 + (quad ^ xr) * 8);
                bk[kt4][1] = *(const bf16x8*)(kp2 + ((quad + 4) ^ xr) * 8);
            }
            bf16x8 bv[2][4];
#pragma unroll
            for (int a = 0; a < 2; ++a)
#pragma unroll
                for (int nt = 0; nt < 4; ++nt)
                    bv[a][nt] = *(const bf16x8*)(vb + (nt * 16 + l16) * 64 + ((a * 4 + quad) ^ xr) * 8);

            // ---- phase 1: QK(mp0) — pure MFMA burst ----
            f32x4 sv0[2][4], sv1[2][4];
            __builtin_amdgcn_s_setprio(1);
#pragma unroll
            for (int mm = 0; mm < 2; ++mm)
#pragma unroll
                for (int kt4 = 0; kt4 < 4; ++kt4) {
                    f32x4 c = mfma_bf16(bk[kt4][0], aq[mm][0], bias4[kt4]);
                    sv0[mm][kt4] = mfma_bf16(bk[kt4][1], aq[mm][1], c);
                }

            // ---- phase 2: exp(mp0) interleaved with QK(mp1) MFMAs ----
#pragma unroll
            for (int kt4 = 0; kt4 < 4; ++kt4) {
                f32x4 c0 = mfma_bf16(bk[kt4][0], aq[2][0], bias4[kt4]);
#pragma unroll
                for (int r = 0; r < 4; ++r)
                    sv0[0][kt4][r] = __builtin_amdgcn_exp2f(sv0[0][kt4][r]);
                f32x4 c1 = mfma_bf16(bk[kt4][0], aq[3][0], bias4[kt4]);
#pragma unroll
                for (int r = 0; r < 4; ++r)
                    sv0[1][kt4][r] = __builtin_amdgcn_exp2f(sv0[1][kt4][r]);
                sv1[0][kt4] = mfma_bf16(bk[kt4][1], aq[2][1], c0);
                sv1[1][kt4] = mfma_bf16(bk[kt4][1], aq[3][1], c1);
            }

            // ---- phase 3: pack+PV(mp0) interleaved with exp(mp1) ----
#pragma unroll
            for (int mm = 0; mm < 2; ++mm) {
#pragma unroll
                for (int a = 0; a < 2; ++a) {
                    bf16x8 pa;
                    pa[0] = f2s(sv0[mm][2*a][0]);   pa[1] = f2s(sv0[mm][2*a][1]);
                    pa[2] = f2s(sv0[mm][2*a][2]);   pa[3] = f2s(sv0[mm][2*a][3]);
                    pa[4] = f2s(sv0[mm][2*a+1][0]); pa[5] = f2s(sv0[mm][2*a+1][1]);
                    pa[6] = f2s(sv0[mm][2*a+1][2]); pa[7] = f2s(sv0[mm][2*a+1][3]);
                    Lacc[mm] = mfma_bf16(pa, ones, Lacc[mm]);
#pragma unroll
                    for (int nt = 0; nt < 4; ++nt)
                        O[mm][nt] = mfma_bf16(pa, bv[a][nt], O[mm][nt]);
                    // 4 TRANS of mp1 after each PV burst (mm,a) -> 16 total (half of sv1)
#pragma unroll
                    for (int r = 0; r < 4; ++r)
                        sv1[mm][2*a + (r >> 1)][(r & 1) + 2*((mm + a) & 1)] =
                            __builtin_amdgcn_exp2f(sv1[mm][2*a + (r >> 1)][(r & 1) + 2*((mm + a) & 1)]);
                }
            }
            // apply exp to the complementary half of sv1
#pragma unroll
            for (int mm = 0; mm < 2; ++mm)
#pragma unroll
                for (int a = 0; a < 2; ++a)
#pragma unroll
                    for (int r = 0; r < 4; ++r) {
                        int kt4 = 2*a + (r >> 1);
                        int ri  = (r & 1) + 2*(((mm + a) & 1) ^ 1);
                        sv1[mm][kt4][ri] = __builtin_amdgcn_exp2f(sv1[mm][kt4][ri]);
                    }

            // ---- phase 4: pack+PV(mp1) ----
#pragma unroll
            for (int mm = 0; mm < 2; ++mm) {
                const int m = 2 + mm;
#pragma unroll
                for (int a = 0; a < 2; ++a) {
                    bf16x8 pa;
                    pa[0] = f2s(sv1[mm][2*a][0]);   pa[1] = f2s(sv1[mm][2*a][1]);
                    pa[2] = f2s(sv1[mm][2*a][2]);   pa[3] = f2s(sv1[mm][2*a][3]);
                    pa[4] = f2s(sv1[mm][2*a+1][0]); pa[5] = f2s(sv1[mm][2*a+1][1]);
                    pa[6] = f2s(sv1[mm][2*a+1][2]); pa[7] = f2s(sv1[mm][2*a+1][3]);
                    Lacc[m] = mfma_bf16(pa, ones, Lacc[m]);
#pragma unroll
                    for (int nt = 0; nt < 4; ++nt)
                        O[m][nt] = mfma_bf16(pa, bv[a][nt], O[m][nt]);
                }
            }
            __builtin_amdgcn_s_setprio(0);
        }

        // k-split combine: kg=1 dumps partials to LDS, kg=0 adds, normalizes, stores.
        __syncthreads();
        float* cb = (float*)&Ks[0][0][0];   // 2 x 4096 floats (32 KB)
        float* lb = (float*)&Vs[0][0][0];   // 2 x 1024 floats
        if (kg == 1) {
#pragma unroll
            for (int m = 0; m < 4; ++m) {
#pragma unroll
                for (int nt = 0; nt < 4; ++nt)
#pragma unroll
                    for (int r = 0; r < 4; ++r)
                        cb[qg * 4096 + (m * 16 + nt * 4 + r) * 64 + lane] = O[m][nt][r];
#pragma unroll
                for (int r = 0; r < 4; ++r)
                    lb[qg * 1024 + (m * 4 + r) * 64 + lane] = Lacc[m][r];
            }
        }
        __syncthreads();
        if (kg == 0) {
#pragma unroll
            for (int m = 0; m < 4; ++m) {
                float inv[4];
#pragma unroll
                for (int r = 0; r < 4; ++r)
                    inv[r] = __builtin_amdgcn_rcpf(Lacc[m][r] + lb[qg * 1024 + (m * 4 + r) * 64 + lane]);
#pragma unroll
                for (int nt = 0; nt < 4; ++nt)
#pragma unroll
                    for (int r = 0; r < 4; ++r) {
                        int row = q0 + qg * 64 + m * 16 + quad * 4 + r;
                        Aout[((size_t)b * 2048 + row) * 1024 + h * 64 + nt * 16 + l16] =
                            __float2bfloat16((O[m][nt][r] + cb[qg * 4096 + (m * 16 + nt * 4 + r) * 64 + lane]) * inv[r]);
                    }
            }
        }
    }

    // ================= grid barrier: all attn output visible =================
    grid_sync(bar, 512u);

    // ================= stage 2: out-proj GEMM (R12 TM=64 form) =================
    {
        constexpr int K = 1024, N = 1024;
        bf16* As_ = &Ks[0][0][0];            //  8 KB
        bf16* Bs_ = &Ks[0][0][0] + 4096;     // 16 KB (total 24 KB <= pool)

        const int wr = wave >> 1, wc = wave & 1;
        // chunked XCD swizzle: XCD X owns bm in [8X, 8X+8), bn-fast ->
        // per-XCD A 1MB + B 2MB = L2-resident.
        const int w3 = (lid & 7) * 64 + (lid >> 3);
        const int bm = w3 >> 3, bn = w3 & 7;

        f32x4 acc[2][4] = {};
        const int crow = lane >> 3;
        const int sblk = (lane & 7) ^ (crow & 7);
        const bf16* gA[2]; const bf16* gB[4]; bf16* lA[2]; bf16* lB[4];
#pragma unroll
        for (int c = 0; c < 2; ++c) {
            int ch = wave * 2 + c;   // 8 chunks x 8 rows = 64 rows
            gA[c] = Aout + (size_t)(bm * 64 + ch * 8 + crow) * K + sblk * 8;
            lA[c] = As_ + ch * 512 + lane * 8;
        }
#pragma unroll
        for (int c = 0; c < 4; ++c) {
            int ch = wave * 4 + c;   // 16 chunks x 8 rows = 128 rows
            gB[c] = WoT + (size_t)(bn * 128 + ch * 8 + crow) * K + sblk * 8;
            lB[c] = Bs_ + ch * 512 + lane * 8;
        }

        for (int k0 = 0; k0 < K; k0 += 64) {
#pragma unroll
            for (int c = 0; c < 2; ++c) gld_lds16(gA[c] + k0, lA[c]);
#pragma unroll
            for (int c = 0; c < 4; ++c) gld_lds16(gB[c] + k0, lB[c]);
            __syncthreads();
#pragma unroll
            for (int ks = 0; ks < 2; ++ks) {
                bf16x8 af[2], bfr[4];
#pragma unroll
                for (int mi = 0; mi < 2; ++mi)
                    af[mi] = *(const bf16x8*)(As_ + (wr * 32 + mi * 16 + l16) * 64 + ((4 * ks + quad) ^ xr) * 8);
#pragma unroll
                for (int ni = 0; ni < 4; ++ni)
                    bfr[ni] = *(const bf16x8*)(Bs_ + (wc * 64 + ni * 16 + l16) * 64 + ((4 * ks + quad) ^ xr) * 8);
#pragma unroll
                for (int mi = 0; mi < 2; ++mi)
#pragma unroll
                    for (int ni = 0; ni < 4; ++ni)
                        acc[mi][ni] = mfma_bf16(af[mi], bfr[ni], acc[mi][ni]);
            }
            __syncthreads();
        }

#pragma unroll
        for (int mi = 0; mi < 2; ++mi)
#pragma unroll
            for (int ni = 0; ni < 4; ++ni) {
                const int col = bn * 128 + wc * 64 + ni * 16 + l16;
                const int row0 = bm * 64 + wr * 32 + mi * 16 + quad * 4;
                const float bs = bo[col];
                const float gm = gamma[col] + 1.0f;
#pragma unroll
                for (int r = 0; r < 4; ++r)
                    Cout[(size_t)(row0 + r) * N + col] = gm * (acc[mi][ni][r] + bs);
            }
    }
}

// ---------------- launcher ----------------
extern "C" void kernel_launch(void* const* d_in, const int* in_sizes, int n_in,
                              void* d_out, int out_size, void* d_ws, size_t ws_size,
                              hipStream_t stream) {
    const float* x     = (const float*)d_in[0];
    const float* gamma = (const float*)d_in[1];
    const int*   mask  = (const int*)d_in[2];
    const float* wqkv  = (const float*)d_in[3];
    const float* bqkv  = (const float*)d_in[4];
    const float* wo    = (const float*)d_in[5];
    const float* bo    = (const float*)d_in[6];
    float* out = (float*)d_out;

    char* ws = (char*)d_ws;
    const size_t MB = 1u << 20;
    bf16* xb    = (bf16*)(ws);            //  8 MB: x cast to bf16      [4096][1024]
    bf16* wqkvT = (bf16*)(ws + 8 * MB);   //  6 MB: W_qkv^T bf16        [3072][1024]
    bf16* woT   = (bf16*)(ws + 14 * MB);  //  2 MB: W_o^T bf16          [1024][1024]
    bf16* Qb    = (bf16*)(ws + 16 * MB);  //  8 MB: Q per head (scaled) [bh][s][dk]
    bf16* Kb    = (bf16*)(ws + 24 * MB);  //  8 MB: K per head          [bh][s][dk]
    bf16* Vt    = (bf16*)(ws + 32 * MB);  //  8 MB: V^T permuted        [bh][dk][s'] (direct from GEMM)
    bf16* attn  = (bf16*)(ws + 40 * MB);  //  8 MB: attention out
    unsigned* bar = (unsigned*)(ws + 48 * MB);   // grid-barrier counter (zeroed by prep)

    prep_kernel<<<8192, 256, 0, stream>>>(x, xb, wqkv, wqkvT, wo, woT, bar);

    // QKV GEMM: [4096,1024] x [1024,3072]; V written transposed+permuted directly
    gemm_bt_kernel<128, 3><<<dim3(24, 32), 256, 0, stream>>>(
        xb, wqkvT, 4096, 3072, 1024, bqkv, Qb, Kb, Vt);

    // fused attention + out-projection (grid barrier between stages)
    attn_out_kernel<<<dim3(16, 32), 256, 0, stream>>>(
        Qb, Kb, Vt, mask, attn, woT, bo, gamma, out, bar);
}

// Round 12
// 210.516 us; speedup vs baseline: 1.0322x; 1.0322x over previous
//
#include <hip/hip_runtime.h>
#include <hip/hip_bf16.h>

// MultiHeadSelfAttention: B=2, S=2048, D=1024, H=16, DK=64
// R18: fix R17's grid-barrier spin. R17 counters: no extra work (MFMA-busy µs
//      match attn+out sum), FETCH/WRITE as predicted — the +40µs was pure stall
//      in the barrier. Mechanism: 512 waves spinning with atomicAdd(bar,0) RMW
//      on ONE cacheline every ~150cy -> coherence point serializes same-line
//      RMWs -> arrival adds queue behind spin traffic. Fix: relaxed device-scope
//      LOAD spin (__hip_atomic_load, no line ownership) + s_sleep(16) (~0.4µs
//      poll period, ~500x less traffic). Stages byte-identical to R17.

using bf16 = __hip_bfloat16;
typedef __attribute__((ext_vector_type(8))) short bf16x8;   // 8 bf16 = 4 VGPRs
typedef __attribute__((ext_vector_type(4))) float f32x4;

#define QSCALE 0.18033688011112042f   // (1/sqrt(64)) * log2(e)

static __device__ __forceinline__ f32x4 mfma_bf16(bf16x8 a, bf16x8 b, f32x4 c) {
    return __builtin_amdgcn_mfma_f32_16x16x32_bf16(a, b, c, 0, 0, 0);
}

static __device__ __forceinline__ void gld_lds16(const void* g, void* s) {
    __builtin_amdgcn_global_load_lds(
        (const __attribute__((address_space(1))) unsigned int*)g,
        (__attribute__((address_space(3))) unsigned int*)s,
        16, 0, 0);
}

static __device__ __forceinline__ short f2s(float f) {
    bf16 h = __float2bfloat16(f);
    return *reinterpret_cast<short*>(&h);
}

// single-use software grid barrier (counter pre-zeroed by prep_kernel).
// Arrival: one device-scope RMW per block. Spin: relaxed device-scope LOAD
// (no cacheline ownership -> no serialization) + s_sleep(16) (~0.4µs poll).
static __device__ __forceinline__ void grid_sync(unsigned* bar, unsigned nblk) {
    __syncthreads();
    if (threadIdx.x == 0) {
        __threadfence();                       // release: publish this block's stores
        atomicAdd(bar, 1u);
        while (__hip_atomic_load(bar, __ATOMIC_RELAXED, __HIP_MEMORY_SCOPE_AGENT) < nblk)
            __builtin_amdgcn_s_sleep(16);
        __threadfence();                       // acquire: see other blocks' stores
    }
    __syncthreads();
}

// ---------------- fused prep: cast x + transpose both weights + barrier init ----------------
__global__ void prep_kernel(const float* __restrict__ x, bf16* __restrict__ xb,
                            const float* __restrict__ wqkv, bf16* __restrict__ wqkvT,
                            const float* __restrict__ wo, bf16* __restrict__ woT,
                            unsigned* __restrict__ bar) {
    __shared__ float tile[32][33];
    int blk = blockIdx.x;
    if (blk == 0 && threadIdx.x == 0) atomicExch(bar, 0u);   // init grid barrier
    if (blk < 4096) {
        int i = blk * 256 + threadIdx.x;
        float4 f = reinterpret_cast<const float4*>(x)[i];
        xb[4*i+0] = __float2bfloat16(f.x);
        xb[4*i+1] = __float2bfloat16(f.y);
        xb[4*i+2] = __float2bfloat16(f.z);
        xb[4*i+3] = __float2bfloat16(f.w);
        return;
    }
    const float* in; bf16* out; int R, C, bx, by;
    if (blk < 7168) {
        int idx = blk - 4096; in = wqkv; out = wqkvT; R = 1024; C = 3072;
        bx = idx % 96; by = idx / 96;
    } else {
        int idx = blk - 7168; in = wo; out = woT; R = 1024; C = 1024;
        bx = idx & 31; by = idx >> 5;
    }
    int c0 = bx * 32, r0 = by * 32;
    int xo = threadIdx.x & 31, yo = threadIdx.x >> 5;   // (32,8)
#pragma unroll
    for (int i = 0; i < 32; i += 8) tile[yo + i][xo] = in[(size_t)(r0 + yo + i) * C + c0 + xo];
    __syncthreads();
#pragma unroll
    for (int i = 0; i < 32; i += 8)
        out[(size_t)(c0 + yo + i) * R + r0 + xo] = __float2bfloat16(tile[xo][yo + i]);
}

// ---------------- QKV GEMM: C[M,N] = A[M,K] @ Bt[N,K]^T  (bf16 in, fp32 acc) ----------------
template <int TM, int MINW>
__global__ __launch_bounds__(256, MINW)
void gemm_bt_kernel(const bf16* __restrict__ A, const bf16* __restrict__ Bt,
                    int M, int N, int K,
                    const float* __restrict__ bias,
                    bf16* __restrict__ Qout, bf16* __restrict__ Kout, bf16* __restrict__ Vout) {
    constexpr int MI = TM / 32;
    constexpr int CA = TM / 32;
    __shared__ __align__(16) bf16 As[TM * 64];
    __shared__ __align__(16) bf16 Bs[128 * 64];

    const int tid  = threadIdx.x;
    const int wave = tid >> 6, lane = tid & 63;
    const int quad = lane >> 4, l16 = lane & 15;
    const int wr = wave >> 1, wc = wave & 1;
    const int bm = blockIdx.y, bn = blockIdx.x;

    f32x4 acc[MI][4] = {};

    const int crow = lane >> 3;
    const int sblk = (lane & 7) ^ (crow & 7);
    const bf16* gA[CA]; const bf16* gB[4]; bf16* lA[CA]; bf16* lB[4];
#pragma unroll
    for (int c = 0; c < CA; ++c) {
        int ch = wave * CA + c;
        gA[c] = A + (size_t)(bm * TM + ch * 8 + crow) * K + sblk * 8;
        lA[c] = As + ch * 512 + lane * 8;
    }
#pragma unroll
    for (int c = 0; c < 4; ++c) {
        int ch = wave * 4 + c;
        gB[c] = Bt + (size_t)(bn * 128 + ch * 8 + crow) * K + sblk * 8;
        lB[c] = Bs + ch * 512 + lane * 8;
    }
    const int xr = l16 & 7;

    for (int k0 = 0; k0 < K; k0 += 64) {
#pragma unroll
        for (int c = 0; c < CA; ++c) gld_lds16(gA[c] + k0, lA[c]);
#pragma unroll
        for (int c = 0; c < 4; ++c) gld_lds16(gB[c] + k0, lB[c]);
        __syncthreads();
#pragma unroll
        for (int ks = 0; ks < 2; ++ks) {
            bf16x8 af[MI], bfr[4];
#pragma unroll
            for (int mi = 0; mi < MI; ++mi)
                af[mi] = *(const bf16x8*)(As + (wr * (TM/2) + mi * 16 + l16) * 64 + ((4 * ks + quad) ^ xr) * 8);
#pragma unroll
            for (int ni = 0; ni < 4; ++ni)
                bfr[ni] = *(const bf16x8*)(Bs + (wc * 64 + ni * 16 + l16) * 64 + ((4 * ks + quad) ^ xr) * 8);
#pragma unroll
            for (int mi = 0; mi < MI; ++mi)
#pragma unroll
                for (int ni = 0; ni < 4; ++ni)
                    acc[mi][ni] = mfma_bf16(af[mi], bfr[ni], acc[mi][ni]);
        }
        __syncthreads();
    }

#pragma unroll
    for (int mi = 0; mi < MI; ++mi) {
#pragma unroll
        for (int ni = 0; ni < 4; ++ni) {
            const int col = bn * 128 + wc * 64 + ni * 16 + l16;
            const int row0 = bm * TM + wr * (TM/2) + mi * 16 + quad * 4;
            const float bs = bias[col];
            float vv[4];
#pragma unroll
            for (int r = 0; r < 4; ++r) vv[r] = acc[mi][ni][r] + bs;
            const int h = col / 192;
            const int rr = col - h * 192;
            const int which = rr >> 6, dk = rr & 63;
            const int b = row0 >> 11, s0 = row0 & 2047;   // S = 2048
            const size_t bh = (size_t)b * 16 + h;
            if (which == 0) {
#pragma unroll
                for (int r = 0; r < 4; ++r)
                    Qout[(bh * 2048 + s0 + r) * 64 + dk] = __float2bfloat16(vv[r] * QSCALE);
            } else if (which == 1) {
#pragma unroll
                for (int r = 0; r < 4; ++r)
                    Kout[(bh * 2048 + s0 + r) * 64 + dk] = __float2bfloat16(vv[r]);
            } else {
                // V^T with kpos permutation (replaces transpose_v kernel):
                // s' = (s&~31) | ((s&12)<<1) | ((s&16)>>2) | (s&3); s0&3==0 so
                // the 4 r-values land at consecutive s' -> one short4 store.
                const int sp0 = (s0 & ~31) | ((s0 & 12) << 1) | ((s0 & 16) >> 2);
                short4 pv;
                pv.x = f2s(vv[0]); pv.y = f2s(vv[1]);
                pv.z = f2s(vv[2]); pv.w = f2s(vv[3]);
                *reinterpret_cast<short4*>(&Vout[(bh * 64 + dk) * 2048 + sp0]) = pv;
            }
        }
    }
}

// ---------------- fused attn (R14, unchanged body) + grid barrier + out-GEMM (TM=64) ----------------
// grid (16,32) = 512 blocks x 256 threads, 2 blocks/CU co-resident.
__global__ __launch_bounds__(256, 2)
void attn_out_kernel(const bf16* __restrict__ Qb, const bf16* __restrict__ Kb,
                     const bf16* __restrict__ Vtp, const int* __restrict__ mask,
                     bf16* __restrict__ Aout,
                     const bf16* __restrict__ WoT, const float* __restrict__ bo,
                     const float* __restrict__ gamma, float* __restrict__ Cout,
                     unsigned* __restrict__ bar) {
    __shared__ __align__(16) bf16 Ks[2][2][4096];   // [pair][tile][kpos*64+dk], XOR-swizzled
    __shared__ __align__(16) bf16 Vs[2][2][4096];   // [pair][tile][dk*64+kpos'], XOR-swizzled
    __shared__ float Biass[2][2][64];

    const int lid = blockIdx.x + (blockIdx.y << 4);
    const int tid = threadIdx.x;
    const int wave = tid >> 6, lane = tid & 63;
    const int quad = lane >> 4, l16 = lane & 15;
    const int xr = l16 & 7;

    // ================= stage 1: attention (R14 body, verified 42.0µs) =================
    {
        const int w   = (lid & 7) * 64 + (lid >> 3);
        const int bh  = w >> 4;
        const int b = bh >> 4, h = bh & 15;
        const int q0 = (w & 15) * 128;
        const int qg = (wave >> 1) & 1, kg = wave & 1;

        // Q fragments: wave owns q rows q0 + qg*64 + m*16 + l16  (m = 0..3)
        bf16x8 aq[4][2];
#pragma unroll
        for (int m = 0; m < 4; ++m) {
            const bf16* qp = Qb + ((size_t)bh * 2048 + q0 + qg * 64 + m * 16 + l16) * 64;
            aq[m][0] = *(const bf16x8*)(qp + quad * 8);
            aq[m][1] = *(const bf16x8*)(qp + 32 + quad * 8);
        }

        bf16x8 ones;
#pragma unroll
        for (int j = 0; j < 8; ++j) ones[j] = (short)0x3F80;   // bf16 1.0

        f32x4 O[4][4] = {};
        f32x4 Lacc[4] = {};

        const int r8 = lane >> 3, b8 = lane & 7;
        const int srcb = b8 ^ r8;
        const bf16* gK = Kb  + ((size_t)bh * 2048 + wave * 8 + r8) * 64 + srcb * 8;
        const bf16* gV = Vtp + ((size_t)bh * 64 + wave * 8 + r8) * 2048 + srcb * 8;
        const int so = wave * 512 + lane * 8;

        // prologue: tiles 0,1 -> pair0; bias tiles 0,1; mask prefetch tiles 2,3
        int mreg = 0;
#pragma unroll
        for (int ti = 0; ti < 2; ++ti)
#pragma unroll
            for (int c = 0; c < 2; ++c) {
                gld_lds16(gK + (size_t)ti * 4096 + c * 2048, &Ks[0][ti][c * 2048 + so]);
                gld_lds16(gV + (size_t)ti * 64 + c * 65536, &Vs[0][ti][c * 2048 + so]);
            }
        if (tid < 128) {
            Biass[0][tid >> 6][tid & 63] = mask[b * 2048 + tid] ? -24.0f : -1e30f;
            mreg = mask[b * 2048 + 128 + tid];
        }

        for (int t = 0; t < 16; ++t) {
            __syncthreads();   // pair[cur] DMA + bias landed; prior reads of pair[nxt] done
            const int cur = t & 1, nxt = cur ^ 1;

            if (t < 15) {
                const int u0 = 2 * t + 2;
#pragma unroll
                for (int ti = 0; ti < 2; ++ti)
#pragma unroll
                    for (int c = 0; c < 2; ++c) {
                        gld_lds16(gK + (size_t)(u0 + ti) * 4096 + c * 2048, &Ks[nxt][ti][c * 2048 + so]);
                        gld_lds16(gV + (size_t)(u0 + ti) * 64 + c * 65536, &Vs[nxt][ti][c * 2048 + so]);
                    }
                if (tid < 128) Biass[nxt][tid >> 6][tid & 63] = mreg ? -24.0f : -1e30f;
            }
            if (t < 14 && tid < 128) mreg = mask[b * 2048 + t * 128 + 256 + tid];

            // this wave's tile = 2t + kg: hoisted fragments (shared across 4 m-groups)
            const bf16* kb = &Ks[cur][kg][0];
            const bf16* vb = &Vs[cur][kg][0];
            f32x4 bias4[4];
            bf16x8 bk[4][2];
#pragma unroll
            for (int kt4 = 0; kt4 < 4; ++kt4) {
                bias4[kt4] = *(const f32x4*)(&Biass[cur][kg][0] + kt4 * 16 + quad * 4);
                const bf16* kp2 = kb + (kt4 * 16 + l16) * 64;
                bk[kt4][0] = *(const bf16x8*)(kp2 + (quad ^ xr) * 8);
                bk[kt4][1] = *(const bf16x8*)(kp2 + ((quad + 4) ^ xr) * 8);
            }
            bf16x8 bv[2][4];
#pragma unroll
            for (int a = 0; a < 2; ++a)
#pragma unroll
                for (int nt = 0; nt < 4; ++nt)
                    bv[a][nt] = *(const bf16x8*)(vb + (nt * 16 + l16) * 64 + ((a * 4 + quad) ^ xr) * 8);

            // ---- phase 1: QK(mp0) — pure MFMA burst ----
            f32x4 sv0[2][4], sv1[2][4];
            __builtin_amdgcn_s_setprio(1);
#pragma unroll
            for (int mm = 0; mm < 2; ++mm)
#pragma unroll
                for (int kt4 = 0; kt4 < 4; ++kt4) {
                    f32x4 c = mfma_bf16(bk[kt4][0], aq[mm][0], bias4[kt4]);
                    sv0[mm][kt4] = mfma_bf16(bk[kt4][1], aq[mm][1], c);
                }

            // ---- phase 2: exp(mp0) interleaved with QK(mp1) MFMAs ----
#pragma unroll
            for (int kt4 = 0; kt4 < 4; ++kt4) {
                f32x4 c0 = mfma_bf16(bk[kt4][0], aq[2][0], bias4[kt4]);
#pragma unroll
                for (int r = 0; r < 4; ++r)
                    sv0[0][kt4][r] = __builtin_amdgcn_exp2f(sv0[0][kt4][r]);
                f32x4 c1 = mfma_bf16(bk[kt4][0], aq[3][0], bias4[kt4]);
#pragma unroll
                for (int r = 0; r < 4; ++r)
                    sv0[1][kt4][r] = __builtin_amdgcn_exp2f(sv0[1][kt4][r]);
                sv1[0][kt4] = mfma_bf16(bk[kt4][1], aq[2][1], c0);
                sv1[1][kt4] = mfma_bf16(bk[kt4][1], aq[3][1], c1);
            }

            // ---- phase 3: pack+PV(mp0) interleaved with exp(mp1) ----
#pragma unroll
            for (int mm = 0; mm < 2; ++mm) {
#pragma unroll
                for (int a = 0; a < 2; ++a) {
                    bf16x8 pa;
                    pa[0] = f2s(sv0[mm][2*a][0]);   pa[1] = f2s(sv0[mm][2*a][1]);
                    pa[2] = f2s(sv0[mm][2*a][2]);   pa[3] = f2s(sv0[mm][2*a][3]);
                    pa[4] = f2s(sv0[mm][2*a+1][0]); pa[5] = f2s(sv0[mm][2*a+1][1]);
                    pa[6] = f2s(sv0[mm][2*a+1][2]); pa[7] = f2s(sv0[mm][2*a+1][3]);
                    Lacc[mm] = mfma_bf16(pa, ones, Lacc[mm]);
#pragma unroll
                    for (int nt = 0; nt < 4; ++nt)
                        O[mm][nt] = mfma_bf16(pa, bv[a][nt], O[mm][nt]);
                    // 4 TRANS of mp1 after each PV burst (mm,a) -> 16 total (half of sv1)
#pragma unroll
                    for (int r = 0; r < 4; ++r)
                        sv1[mm][2*a + (r >> 1)][(r & 1) + 2*((mm + a) & 1)] =
                            __builtin_amdgcn_exp2f(sv1[mm][2*a + (r >> 1)][(r & 1) + 2*((mm + a) & 1)]);
                }
            }
            // apply exp to the complementary half of sv1
#pragma unroll
            for (int mm = 0; mm < 2; ++mm)
#pragma unroll
                for (int a = 0; a < 2; ++a)
#pragma unroll
                    for (int r = 0; r < 4; ++r) {
                        int kt4 = 2*a + (r >> 1);
                        int ri  = (r & 1) + 2*(((mm + a) & 1) ^ 1);
                        sv1[mm][kt4][ri] = __builtin_amdgcn_exp2f(sv1[mm][kt4][ri]);
                    }

            // ---- phase 4: pack+PV(mp1) ----
#pragma unroll
            for (int mm = 0; mm < 2; ++mm) {
                const int m = 2 + mm;
#pragma unroll
                for (int a = 0; a < 2; ++a) {
                    bf16x8 pa;
                    pa[0] = f2s(sv1[mm][2*a][0]);   pa[1] = f2s(sv1[mm][2*a][1]);
                    pa[2] = f2s(sv1[mm][2*a][2]);   pa[3] = f2s(sv1[mm][2*a][3]);
                    pa[4] = f2s(sv1[mm][2*a+1][0]); pa[5] = f2s(sv1[mm][2*a+1][1]);
                    pa[6] = f2s(sv1[mm][2*a+1][2]); pa[7] = f2s(sv1[mm][2*a+1][3]);
                    Lacc[m] = mfma_bf16(pa, ones, Lacc[m]);
#pragma unroll
                    for (int nt = 0; nt < 4; ++nt)
                        O[m][nt] = mfma_bf16(pa, bv[a][nt], O[m][nt]);
                }
            }
            __builtin_amdgcn_s_setprio(0);
        }

        // k-split combine: kg=1 dumps partials to LDS, kg=0 adds, normalizes, stores.
        __syncthreads();
        float* cb = (float*)&Ks[0][0][0];   // 2 x 4096 floats (32 KB)
        float* lb = (float*)&Vs[0][0][0];   // 2 x 1024 floats
        if (kg == 1) {
#pragma unroll
            for (int m = 0; m < 4; ++m) {
#pragma unroll
                for (int nt = 0; nt < 4; ++nt)
#pragma unroll
                    for (int r = 0; r < 4; ++r)
                        cb[qg * 4096 + (m * 16 + nt * 4 + r) * 64 + lane] = O[m][nt][r];
#pragma unroll
                for (int r = 0; r < 4; ++r)
                    lb[qg * 1024 + (m * 4 + r) * 64 + lane] = Lacc[m][r];
            }
        }
        __syncthreads();
        if (kg == 0) {
#pragma unroll
            for (int m = 0; m < 4; ++m) {
                float inv[4];
#pragma unroll
                for (int r = 0; r < 4; ++r)
                    inv[r] = __builtin_amdgcn_rcpf(Lacc[m][r] + lb[qg * 1024 + (m * 4 + r) * 64 + lane]);
#pragma unroll
                for (int nt = 0; nt < 4; ++nt)
#pragma unroll
                    for (int r = 0; r < 4; ++r) {
                        int row = q0 + qg * 64 + m * 16 + quad * 4 + r;
                        Aout[((size_t)b * 2048 + row) * 1024 + h * 64 + nt * 16 + l16] =
                            __float2bfloat16((O[m][nt][r] + cb[qg * 4096 + (m * 16 + nt * 4 + r) * 64 + lane]) * inv[r]);
                    }
            }
        }
    }

    // ================= grid barrier: all attn output visible =================
    grid_sync(bar, 512u);

    // ================= stage 2: out-proj GEMM (R12 TM=64 form) =================
    {
        constexpr int K = 1024, N = 1024;
        bf16* As_ = &Ks[0][0][0];            //  8 KB
        bf16* Bs_ = &Ks[0][0][0] + 4096;     // 16 KB (total 24 KB <= pool)

        const int wr = wave >> 1, wc = wave & 1;
        // chunked XCD swizzle: XCD X owns bm in [8X, 8X+8), bn-fast ->
        // per-XCD A 1MB + B 2MB = L2-resident.
        const int w3 = (lid & 7) * 64 + (lid >> 3);
        const int bm = w3 >> 3, bn = w3 & 7;

        f32x4 acc[2][4] = {};
        const int crow = lane >> 3;
        const int sblk = (lane & 7) ^ (crow & 7);
        const bf16* gA[2]; const bf16* gB[4]; bf16* lA[2]; bf16* lB[4];
#pragma unroll
        for (int c = 0; c < 2; ++c) {
            int ch = wave * 2 + c;   // 8 chunks x 8 rows = 64 rows
            gA[c] = Aout + (size_t)(bm * 64 + ch * 8 + crow) * K + sblk * 8;
            lA[c] = As_ + ch * 512 + lane * 8;
        }
#pragma unroll
        for (int c = 0; c < 4; ++c) {
            int ch = wave * 4 + c;   // 16 chunks x 8 rows = 128 rows
            gB[c] = WoT + (size_t)(bn * 128 + ch * 8 + crow) * K + sblk * 8;
            lB[c] = Bs_ + ch * 512 + lane * 8;
        }

        for (int k0 = 0; k0 < K; k0 += 64) {
#pragma unroll
            for (int c = 0; c < 2; ++c) gld_lds16(gA[c] + k0, lA[c]);
#pragma unroll
            for (int c = 0; c < 4; ++c) gld_lds16(gB[c] + k0, lB[c]);
            __syncthreads();
#pragma unroll
            for (int ks = 0; ks < 2; ++ks) {
                bf16x8 af[2], bfr[4];
#pragma unroll
                for (int mi = 0; mi < 2; ++mi)
                    af[mi] = *(const bf16x8*)(As_ + (wr * 32 + mi * 16 + l16) * 64 + ((4 * ks + quad) ^ xr) * 8);
#pragma unroll
                for (int ni = 0; ni < 4; ++ni)
                    bfr[ni] = *(const bf16x8*)(Bs_ + (wc * 64 + ni * 16 + l16) * 64 + ((4 * ks + quad) ^ xr) * 8);
#pragma unroll
                for (int mi = 0; mi < 2; ++mi)
#pragma unroll
                    for (int ni = 0; ni < 4; ++ni)
                        acc[mi][ni] = mfma_bf16(af[mi], bfr[ni], acc[mi][ni]);
            }
            __syncthreads();
        }

#pragma unroll
        for (int mi = 0; mi < 2; ++mi)
#pragma unroll
            for (int ni = 0; ni < 4; ++ni) {
                const int col = bn * 128 + wc * 64 + ni * 16 + l16;
                const int row0 = bm * 64 + wr * 32 + mi * 16 + quad * 4;
                const float bs = bo[col];
                const float gm = gamma[col] + 1.0f;
#pragma unroll
                for (int r = 0; r < 4; ++r)
                    Cout[(size_t)(row0 + r) * N + col] = gm * (acc[mi][ni][r] + bs);
            }
    }
}

// ---------------- launcher ----------------
extern "C" void kernel_launch(void* const* d_in, const int* in_sizes, int n_in,
                              void* d_out, int out_size, void* d_ws, size_t ws_size,
                              hipStream_t stream) {
    const float* x     = (const float*)d_in[0];
    const float* gamma = (const float*)d_in[1];
    const int*   mask  = (const int*)d_in[2];
    const float* wqkv  = (const float*)d_in[3];
    const float* bqkv  = (const float*)d_in[4];
    const float* wo    = (const float*)d_in[5];
    const float* bo    = (const float*)d_in[6];
    float* out = (float*)d_out;

    char* ws = (char*)d_ws;
    const size_t MB = 1u << 20;
    bf16* xb    = (bf16*)(ws);            //  8 MB: x cast to bf16      [4096][1024]
    bf16* wqkvT = (bf16*)(ws + 8 * MB);   //  6 MB: W_qkv^T bf16        [3072][1024]
    bf16* woT   = (bf16*)(ws + 14 * MB);  //  2 MB: W_o^T bf16          [1024][1024]
    bf16* Qb    = (bf16*)(ws + 16 * MB);  //  8 MB: Q per head (scaled) [bh][s][dk]
    bf16* Kb    = (bf16*)(ws + 24 * MB);  //  8 MB: K per head          [bh][s][dk]
    bf16* Vt    = (bf16*)(ws + 32 * MB);  //  8 MB: V^T permuted        [bh][dk][s'] (direct from GEMM)
    bf16* attn  = (bf16*)(ws + 40 * MB);  //  8 MB: attention out
    unsigned* bar = (unsigned*)(ws + 48 * MB);   // grid-barrier counter (zeroed by prep)

    prep_kernel<<<8192, 256, 0, stream>>>(x, xb, wqkv, wqkvT, wo, woT, bar);

    // QKV GEMM: [4096,1024] x [1024,3072]; V written transposed+permuted directly
    gemm_bt_kernel<128, 3><<<dim3(24, 32), 256, 0, stream>>>(
        xb, wqkvT, 4096, 3072, 1024, bqkv, Qb, Kb, Vt);

    // fused attention + out-projection (grid barrier between stages)
    attn_out_kernel<<<dim3(16, 32), 256, 0, stream>>>(
        Qb, Kb, Vt, mask, attn, woT, bo, gamma, out, bar);
}

// Round 14
// 173.345 us; speedup vs baseline: 1.2535x; 1.2144x over previous
//
#include <hip/hip_runtime.h>
#include <hip/hip_bf16.h>

// MultiHeadSelfAttention: B=2, S=2048, D=1024, H=16, DK=64
// R20: resubmit R16/R19 verified-best config unchanged (R13-round bench was an
//      infra failure: "container failed twice", no kernel signal). Banked:
//      R14 attn (42.0µs: TRANS/MFMA interleave, k-split waves, XCD swizzle,
//      L2-resident K/V) + R12 QKV (fused V^T epilogue) + R13 out-GEMM
//      (512-thr 128x128, chunked XCD swizzle) + prep. 172.1-174.3µs verified.

using bf16 = __hip_bfloat16;
typedef __attribute__((ext_vector_type(8))) short bf16x8;   // 8 bf16 = 4 VGPRs
typedef __attribute__((ext_vector_type(4))) float f32x4;

#define QSCALE 0.18033688011112042f   // (1/sqrt(64)) * log2(e)

static __device__ __forceinline__ f32x4 mfma_bf16(bf16x8 a, bf16x8 b, f32x4 c) {
    return __builtin_amdgcn_mfma_f32_16x16x32_bf16(a, b, c, 0, 0, 0);
}

static __device__ __forceinline__ void gld_lds16(const void* g, void* s) {
    __builtin_amdgcn_global_load_lds(
        (const __attribute__((address_space(1))) unsigned int*)g,
        (__attribute__((address_space(3))) unsigned int*)s,
        16, 0, 0);
}

static __device__ __forceinline__ short f2s(float f) {
    bf16 h = __float2bfloat16(f);
    return *reinterpret_cast<short*>(&h);
}

// ---------------- fused prep: cast x + transpose both weights ----------------
__global__ void prep_kernel(const float* __restrict__ x, bf16* __restrict__ xb,
                            const float* __restrict__ wqkv, bf16* __restrict__ wqkvT,
                            const float* __restrict__ wo, bf16* __restrict__ woT) {
    __shared__ float tile[32][33];
    int blk = blockIdx.x;
    if (blk < 4096) {
        int i = blk * 256 + threadIdx.x;
        float4 f = reinterpret_cast<const float4*>(x)[i];
        xb[4*i+0] = __float2bfloat16(f.x);
        xb[4*i+1] = __float2bfloat16(f.y);
        xb[4*i+2] = __float2bfloat16(f.z);
        xb[4*i+3] = __float2bfloat16(f.w);
        return;
    }
    const float* in; bf16* out; int R, C, bx, by;
    if (blk < 7168) {
        int idx = blk - 4096; in = wqkv; out = wqkvT; R = 1024; C = 3072;
        bx = idx % 96; by = idx / 96;
    } else {
        int idx = blk - 7168; in = wo; out = woT; R = 1024; C = 1024;
        bx = idx & 31; by = idx >> 5;
    }
    int c0 = bx * 32, r0 = by * 32;
    int xo = threadIdx.x & 31, yo = threadIdx.x >> 5;   // (32,8)
#pragma unroll
    for (int i = 0; i < 32; i += 8) tile[yo + i][xo] = in[(size_t)(r0 + yo + i) * C + c0 + xo];
    __syncthreads();
#pragma unroll
    for (int i = 0; i < 32; i += 8)
        out[(size_t)(c0 + yo + i) * R + r0 + xo] = __float2bfloat16(tile[xo][yo + i]);
}

// ---------------- QKV GEMM: C[M,N] = A[M,K] @ Bt[N,K]^T  (bf16 in, fp32 acc) ----------------
template <int TM, int MINW>
__global__ __launch_bounds__(256, MINW)
void gemm_bt_kernel(const bf16* __restrict__ A, const bf16* __restrict__ Bt,
                    int M, int N, int K,
                    const float* __restrict__ bias,
                    bf16* __restrict__ Qout, bf16* __restrict__ Kout, bf16* __restrict__ Vout) {
    constexpr int MI = TM / 32;
    constexpr int CA = TM / 32;
    __shared__ __align__(16) bf16 As[TM * 64];
    __shared__ __align__(16) bf16 Bs[128 * 64];

    const int tid  = threadIdx.x;
    const int wave = tid >> 6, lane = tid & 63;
    const int quad = lane >> 4, l16 = lane & 15;
    const int wr = wave >> 1, wc = wave & 1;
    const int bm = blockIdx.y, bn = blockIdx.x;

    f32x4 acc[MI][4] = {};

    const int crow = lane >> 3;
    const int sblk = (lane & 7) ^ (crow & 7);
    const bf16* gA[CA]; const bf16* gB[4]; bf16* lA[CA]; bf16* lB[4];
#pragma unroll
    for (int c = 0; c < CA; ++c) {
        int ch = wave * CA + c;
        gA[c] = A + (size_t)(bm * TM + ch * 8 + crow) * K + sblk * 8;
        lA[c] = As + ch * 512 + lane * 8;
    }
#pragma unroll
    for (int c = 0; c < 4; ++c) {
        int ch = wave * 4 + c;
        gB[c] = Bt + (size_t)(bn * 128 + ch * 8 + crow) * K + sblk * 8;
        lB[c] = Bs + ch * 512 + lane * 8;
    }
    const int xr = l16 & 7;

    for (int k0 = 0; k0 < K; k0 += 64) {
#pragma unroll
        for (int c = 0; c < CA; ++c) gld_lds16(gA[c] + k0, lA[c]);
#pragma unroll
        for (int c = 0; c < 4; ++c) gld_lds16(gB[c] + k0, lB[c]);
        __syncthreads();
#pragma unroll
        for (int ks = 0; ks < 2; ++ks) {
            bf16x8 af[MI], bfr[4];
#pragma unroll
            for (int mi = 0; mi < MI; ++mi)
                af[mi] = *(const bf16x8*)(As + (wr * (TM/2) + mi * 16 + l16) * 64 + ((4 * ks + quad) ^ xr) * 8);
#pragma unroll
            for (int ni = 0; ni < 4; ++ni)
                bfr[ni] = *(const bf16x8*)(Bs + (wc * 64 + ni * 16 + l16) * 64 + ((4 * ks + quad) ^ xr) * 8);
#pragma unroll
            for (int mi = 0; mi < MI; ++mi)
#pragma unroll
                for (int ni = 0; ni < 4; ++ni)
                    acc[mi][ni] = mfma_bf16(af[mi], bfr[ni], acc[mi][ni]);
        }
        __syncthreads();
    }

#pragma unroll
    for (int mi = 0; mi < MI; ++mi) {
#pragma unroll
        for (int ni = 0; ni < 4; ++ni) {
            const int col = bn * 128 + wc * 64 + ni * 16 + l16;
            const int row0 = bm * TM + wr * (TM/2) + mi * 16 + quad * 4;
            const float bs = bias[col];
            float vv[4];
#pragma unroll
            for (int r = 0; r < 4; ++r) vv[r] = acc[mi][ni][r] + bs;
            const int h = col / 192;
            const int rr = col - h * 192;
            const int which = rr >> 6, dk = rr & 63;
            const int b = row0 >> 11, s0 = row0 & 2047;   // S = 2048
            const size_t bh = (size_t)b * 16 + h;
            if (which == 0) {
#pragma unroll
                for (int r = 0; r < 4; ++r)
                    Qout[(bh * 2048 + s0 + r) * 64 + dk] = __float2bfloat16(vv[r] * QSCALE);
            } else if (which == 1) {
#pragma unroll
                for (int r = 0; r < 4; ++r)
                    Kout[(bh * 2048 + s0 + r) * 64 + dk] = __float2bfloat16(vv[r]);
            } else {
                // V^T with kpos permutation (replaces transpose_v kernel):
                // s' = (s&~31) | ((s&12)<<1) | ((s&16)>>2) | (s&3); s0&3==0 so
                // the 4 r-values land at consecutive s' -> one short4 store.
                const int sp0 = (s0 & ~31) | ((s0 & 12) << 1) | ((s0 & 16) >> 2);
                short4 pv;
                pv.x = f2s(vv[0]); pv.y = f2s(vv[1]);
                pv.z = f2s(vv[2]); pv.w = f2s(vv[3]);
                *reinterpret_cast<short4*>(&Vout[(bh * 64 + dk) * 2048 + sp0]) = pv;
            }
        }
    }
}

// ---------------- out-proj GEMM: 512 threads, 128x128 tile, 8 waves ----------------
__global__ __launch_bounds__(512, 2)
void gemm_out_kernel(const bf16* __restrict__ A, const bf16* __restrict__ Bt,
                     const float* __restrict__ bias, const float* __restrict__ gamma,
                     float* __restrict__ Cout) {
    constexpr int K = 1024, N = 1024;
    __shared__ __align__(16) bf16 As[128 * 64];
    __shared__ __align__(16) bf16 Bs[128 * 64];

    const int tid = threadIdx.x;
    const int wave = tid >> 6, lane = tid & 63;
    const int quad = lane >> 4, l16 = lane & 15;
    const int wr = wave >> 1, wc = wave & 1;

    const int lid = blockIdx.x + (blockIdx.y << 3);   // grid (8, 32) = 256 blocks
    const int w = (lid & 7) * 32 + (lid >> 3);        // bijective chunked swizzle
    const int bm = w >> 3, bn = w & 7;

    f32x4 acc[2][4] = {};

    const int crow = lane >> 3;
    const int sblk = (lane & 7) ^ (crow & 7);
    const bf16* gA[2]; const bf16* gB[2]; bf16* lA[2]; bf16* lB[2];
#pragma unroll
    for (int c = 0; c < 2; ++c) {
        int ch = wave * 2 + c;   // 16 chunks x 8 rows = 128 rows
        gA[c] = A + (size_t)(bm * 128 + ch * 8 + crow) * K + sblk * 8;
        lA[c] = As + ch * 512 + lane * 8;
        gB[c] = Bt + (size_t)(bn * 128 + ch * 8 + crow) * K + sblk * 8;
        lB[c] = Bs + ch * 512 + lane * 8;
    }
    const int xr = l16 & 7;

    for (int k0 = 0; k0 < K; k0 += 64) {
#pragma unroll
        for (int c = 0; c < 2; ++c) {
            gld_lds16(gA[c] + k0, lA[c]);
            gld_lds16(gB[c] + k0, lB[c]);
        }
        __syncthreads();
#pragma unroll
        for (int ks = 0; ks < 2; ++ks) {
            bf16x8 af[2], bfr[4];
#pragma unroll
            for (int mi = 0; mi < 2; ++mi)
                af[mi] = *(const bf16x8*)(As + (wr * 32 + mi * 16 + l16) * 64 + ((4 * ks + quad) ^ xr) * 8);
#pragma unroll
            for (int ni = 0; ni < 4; ++ni)
                bfr[ni] = *(const bf16x8*)(Bs + (wc * 64 + ni * 16 + l16) * 64 + ((4 * ks + quad) ^ xr) * 8);
#pragma unroll
            for (int mi = 0; mi < 2; ++mi)
#pragma unroll
                for (int ni = 0; ni < 4; ++ni)
                    acc[mi][ni] = mfma_bf16(af[mi], bfr[ni], acc[mi][ni]);
        }
        __syncthreads();
    }

#pragma unroll
    for (int mi = 0; mi < 2; ++mi)
#pragma unroll
        for (int ni = 0; ni < 4; ++ni) {
            const int col = bn * 128 + wc * 64 + ni * 16 + l16;
            const int row0 = bm * 128 + wr * 32 + mi * 16 + quad * 4;
            const float bs = bias[col];
            const float gm = gamma[col] + 1.0f;
#pragma unroll
            for (int r = 0; r < 4; ++r)
                Cout[(size_t)(row0 + r) * N + col] = gm * (acc[mi][ni][r] + bs);
        }
}

// ---------------- flash attention: 2 q-groups x 2 k-groups, pair-dbuf DMA ----------------
// R14 (verified 42.0µs): per-tile compute reordered for pipe overlap:
//   QK(mp0) -> [exp(mp0) ⊕ QK(mp1) interleaved] -> [pack/PV(mp0) ⊕ exp(mp1)] -> pack/PV(mp1)
__global__ __launch_bounds__(256, 2)
void attn_kernel(const bf16* __restrict__ Qb, const bf16* __restrict__ Kb,
                 const bf16* __restrict__ Vtp, const int* __restrict__ mask,
                 bf16* __restrict__ Aout) {
    __shared__ __align__(16) bf16 Ks[2][2][4096];   // [pair][tile][kpos*64+dk], XOR-swizzled
    __shared__ __align__(16) bf16 Vs[2][2][4096];   // [pair][tile][dk*64+kpos'], XOR-swizzled
    __shared__ float Biass[2][2][64];

    const int lid = blockIdx.x + (blockIdx.y << 4);
    const int w   = (lid & 7) * 64 + (lid >> 3);
    const int bh  = w >> 4;
    const int b = bh >> 4, h = bh & 15;
    const int q0 = (w & 15) * 128;
    const int tid = threadIdx.x;
    const int wave = tid >> 6, lane = tid & 63;
    const int qg = wave >> 1, kg = wave & 1;
    const int quad = lane >> 4, l16 = lane & 15;
    const int xr = l16 & 7;

    // Q fragments: wave owns q rows q0 + qg*64 + m*16 + l16  (m = 0..3)
    bf16x8 aq[4][2];
#pragma unroll
    for (int m = 0; m < 4; ++m) {
        const bf16* qp = Qb + ((size_t)bh * 2048 + q0 + qg * 64 + m * 16 + l16) * 64;
        aq[m][0] = *(const bf16x8*)(qp + quad * 8);
        aq[m][1] = *(const bf16x8*)(qp + 32 + quad * 8);
    }

    bf16x8 ones;
#pragma unroll
    for (int j = 0; j < 8; ++j) ones[j] = (short)0x3F80;   // bf16 1.0

    f32x4 O[4][4] = {};
    f32x4 Lacc[4] = {};

    const int r8 = lane >> 3, b8 = lane & 7;
    const int srcb = b8 ^ r8;
    const bf16* gK = Kb  + ((size_t)bh * 2048 + wave * 8 + r8) * 64 + srcb * 8;
    const bf16* gV = Vtp + ((size_t)bh * 64 + wave * 8 + r8) * 2048 + srcb * 8;
    const int so = wave * 512 + lane * 8;

    // prologue: tiles 0,1 -> pair0; bias tiles 0,1; mask prefetch tiles 2,3
    int mreg = 0;
#pragma unroll
    for (int ti = 0; ti < 2; ++ti)
#pragma unroll
        for (int c = 0; c < 2; ++c) {
            gld_lds16(gK + (size_t)ti * 4096 + c * 2048, &Ks[0][ti][c * 2048 + so]);
            gld_lds16(gV + (size_t)ti * 64 + c * 65536, &Vs[0][ti][c * 2048 + so]);
        }
    if (tid < 128) {
        Biass[0][tid >> 6][tid & 63] = mask[b * 2048 + tid] ? -24.0f : -1e30f;
        mreg = mask[b * 2048 + 128 + tid];
    }

    for (int t = 0; t < 16; ++t) {
        __syncthreads();   // pair[cur] DMA + bias landed; prior reads of pair[nxt] done
        const int cur = t & 1, nxt = cur ^ 1;

        if (t < 15) {
            const int u0 = 2 * t + 2;
#pragma unroll
            for (int ti = 0; ti < 2; ++ti)
#pragma unroll
                for (int c = 0; c < 2; ++c) {
                    gld_lds16(gK + (size_t)(u0 + ti) * 4096 + c * 2048, &Ks[nxt][ti][c * 2048 + so]);
                    gld_lds16(gV + (size_t)(u0 + ti) * 64 + c * 65536, &Vs[nxt][ti][c * 2048 + so]);
                }
            if (tid < 128) Biass[nxt][tid >> 6][tid & 63] = mreg ? -24.0f : -1e30f;
        }
        if (t < 14 && tid < 128) mreg = mask[b * 2048 + t * 128 + 256 + tid];

        // this wave's tile = 2t + kg: hoisted fragments (shared across 4 m-groups)
        const bf16* kb = &Ks[cur][kg][0];
        const bf16* vb = &Vs[cur][kg][0];
        f32x4 bias4[4];
        bf16x8 bk[4][2];
#pragma unroll
        for (int kt4 = 0; kt4 < 4; ++kt4) {
            bias4[kt4] = *(const f32x4*)(&Biass[cur][kg][0] + kt4 * 16 + quad * 4);
            const bf16* kp2 = kb + (kt4 * 16 + l16) * 64;
            bk[kt4][0] = *(const bf16x8*)(kp2 + (quad ^ xr) * 8);
            bk[kt4][1] = *(const bf16x8*)(kp2 + ((quad + 4) ^ xr) * 8);
        }
        bf16x8 bv[2][4];
#pragma unroll
        for (int a = 0; a < 2; ++a)
#pragma unroll
            for (int nt = 0; nt < 4; ++nt)
                bv[a][nt] = *(const bf16x8*)(vb + (nt * 16 + l16) * 64 + ((a * 4 + quad) ^ xr) * 8);

        // ---- phase 1: QK(mp0) — pure MFMA burst ----
        f32x4 sv0[2][4], sv1[2][4];
        __builtin_amdgcn_s_setprio(1);
#pragma unroll
        for (int mm = 0; mm < 2; ++mm)
#pragma unroll
            for (int kt4 = 0; kt4 < 4; ++kt4) {
                f32x4 c = mfma_bf16(bk[kt4][0], aq[mm][0], bias4[kt4]);
                sv0[mm][kt4] = mfma_bf16(bk[kt4][1], aq[mm][1], c);
            }

        // ---- phase 2: exp(mp0) interleaved with QK(mp1) MFMAs ----
#pragma unroll
        for (int kt4 = 0; kt4 < 4; ++kt4) {
            f32x4 c0 = mfma_bf16(bk[kt4][0], aq[2][0], bias4[kt4]);
#pragma unroll
            for (int r = 0; r < 4; ++r)
                sv0[0][kt4][r] = __builtin_amdgcn_exp2f(sv0[0][kt4][r]);
            f32x4 c1 = mfma_bf16(bk[kt4][0], aq[3][0], bias4[kt4]);
#pragma unroll
            for (int r = 0; r < 4; ++r)
                sv0[1][kt4][r] = __builtin_amdgcn_exp2f(sv0[1][kt4][r]);
            sv1[0][kt4] = mfma_bf16(bk[kt4][1], aq[2][1], c0);
            sv1[1][kt4] = mfma_bf16(bk[kt4][1], aq[3][1], c1);
        }

        // ---- phase 3: pack+PV(mp0) interleaved with exp(mp1) ----
#pragma unroll
        for (int mm = 0; mm < 2; ++mm) {
#pragma unroll
            for (int a = 0; a < 2; ++a) {
                bf16x8 pa;
                pa[0] = f2s(sv0[mm][2*a][0]);   pa[1] = f2s(sv0[mm][2*a][1]);
                pa[2] = f2s(sv0[mm][2*a][2]);   pa[3] = f2s(sv0[mm][2*a][3]);
                pa[4] = f2s(sv0[mm][2*a+1][0]); pa[5] = f2s(sv0[mm][2*a+1][1]);
                pa[6] = f2s(sv0[mm][2*a+1][2]); pa[7] = f2s(sv0[mm][2*a+1][3]);
                Lacc[mm] = mfma_bf16(pa, ones, Lacc[mm]);
#pragma unroll
                for (int nt = 0; nt < 4; ++nt)
                    O[mm][nt] = mfma_bf16(pa, bv[a][nt], O[mm][nt]);
                // 4 TRANS of mp1 after each PV burst (mm,a) -> 16 total (half of sv1)
#pragma unroll
                for (int r = 0; r < 4; ++r)
                    sv1[mm][2*a + (r >> 1)][(r & 1) + 2*((mm + a) & 1)] =
                        __builtin_amdgcn_exp2f(sv1[mm][2*a + (r >> 1)][(r & 1) + 2*((mm + a) & 1)]);
            }
        }
        // apply exp to the complementary half of sv1
#pragma unroll
        for (int mm = 0; mm < 2; ++mm)
#pragma unroll
            for (int a = 0; a < 2; ++a)
#pragma unroll
                for (int r = 0; r < 4; ++r) {
                    int kt4 = 2*a + (r >> 1);
                    int ri  = (r & 1) + 2*(((mm + a) & 1) ^ 1);
                    sv1[mm][kt4][ri] = __builtin_amdgcn_exp2f(sv1[mm][kt4][ri]);
                }

        // ---- phase 4: pack+PV(mp1) ----
#pragma unroll
        for (int mm = 0; mm < 2; ++mm) {
            const int m = 2 + mm;
#pragma unroll
            for (int a = 0; a < 2; ++a) {
                bf16x8 pa;
                pa[0] = f2s(sv1[mm][2*a][0]);   pa[1] = f2s(sv1[mm][2*a][1]);
                pa[2] = f2s(sv1[mm][2*a][2]);   pa[3] = f2s(sv1[mm][2*a][3]);
                pa[4] = f2s(sv1[mm][2*a+1][0]); pa[5] = f2s(sv1[mm][2*a+1][1]);
                pa[6] = f2s(sv1[mm][2*a+1][2]); pa[7] = f2s(sv1[mm][2*a+1][3]);
                Lacc[m] = mfma_bf16(pa, ones, Lacc[m]);
#pragma unroll
                for (int nt = 0; nt < 4; ++nt)
                    O[m][nt] = mfma_bf16(pa, bv[a][nt], O[m][nt]);
            }
        }
        __builtin_amdgcn_s_setprio(0);
    }

    // k-split combine: kg=1 dumps partials to LDS (lane-major, conflict-free),
    // kg=0 adds its own, normalizes, stores.
    __syncthreads();
    float* cb = (float*)&Ks[0][0][0];   // 2 x 4096 floats (32 KB)
    float* lb = (float*)&Vs[0][0][0];   // 2 x 1024 floats
    if (kg == 1) {
#pragma unroll
        for (int m = 0; m < 4; ++m) {
#pragma unroll
            for (int nt = 0; nt < 4; ++nt)
#pragma unroll
                for (int r = 0; r < 4; ++r)
                    cb[qg * 4096 + (m * 16 + nt * 4 + r) * 64 + lane] = O[m][nt][r];
#pragma unroll
            for (int r = 0; r < 4; ++r)
                lb[qg * 1024 + (m * 4 + r) * 64 + lane] = Lacc[m][r];
        }
    }
    __syncthreads();
    if (kg == 0) {
#pragma unroll
        for (int m = 0; m < 4; ++m) {
            float inv[4];
#pragma unroll
            for (int r = 0; r < 4; ++r)
                inv[r] = __builtin_amdgcn_rcpf(Lacc[m][r] + lb[qg * 1024 + (m * 4 + r) * 64 + lane]);
#pragma unroll
            for (int nt = 0; nt < 4; ++nt)
#pragma unroll
                for (int r = 0; r < 4; ++r) {
                    int row = q0 + qg * 64 + m * 16 + quad * 4 + r;
                    float o = O[m][nt][r] + cb[qg * 4096 + (m * 16 + nt * 4 + r) * 64 + lane];
                    Aout[((size_t)b * 2048 + row) * 1024 + h * 64 + nt * 16 + l16] =
                        __float2bfloat16(o * inv[r]);
                }
        }
    }
}

// ---------------- launcher ----------------
extern "C" void kernel_launch(void* const* d_in, const int* in_sizes, int n_in,
                              void* d_out, int out_size, void* d_ws, size_t ws_size,
                              hipStream_t stream) {
    const float* x     = (const float*)d_in[0];
    const float* gamma = (const float*)d_in[1];
    const int*   mask  = (const int*)d_in[2];
    const float* wqkv  = (const float*)d_in[3];
    const float* bqkv  = (const float*)d_in[4];
    const float* wo    = (const float*)d_in[5];
    const float* bo    = (const float*)d_in[6];
    float* out = (float*)d_out;

    char* ws = (char*)d_ws;
    const size_t MB = 1u << 20;
    bf16* xb    = (bf16*)(ws);            //  8 MB: x cast to bf16      [4096][1024]
    bf16* wqkvT = (bf16*)(ws + 8 * MB);   //  6 MB: W_qkv^T bf16        [3072][1024]
    bf16* woT   = (bf16*)(ws + 14 * MB);  //  2 MB: W_o^T bf16          [1024][1024]
    bf16* Qb    = (bf16*)(ws + 16 * MB);  //  8 MB: Q per head (scaled) [bh][s][dk]
    bf16* Kb    = (bf16*)(ws + 24 * MB);  //  8 MB: K per head          [bh][s][dk]
    bf16* Vt    = (bf16*)(ws + 32 * MB);  //  8 MB: V^T permuted        [bh][dk][s'] (direct from GEMM)
    bf16* attn  = (bf16*)(ws + 40 * MB);  //  8 MB: attention out

    prep_kernel<<<8192, 256, 0, stream>>>(x, xb, wqkv, wqkvT, wo, woT);

    // QKV GEMM: [4096,1024] x [1024,3072]; V written transposed+permuted directly
    gemm_bt_kernel<128, 3><<<dim3(24, 32), 256, 0, stream>>>(
        xb, wqkvT, 4096, 3072, 1024, bqkv, Qb, Kb, Vt);

    // attention: grid (S/128, B*H), 256-thread blocks (2 qg x 2 kg waves)
    attn_kernel<<<dim3(16, 32), 256, 0, stream>>>(Qb, Kb, Vt, mask, attn);

    // out GEMM: [4096,1024] x [1024,1024], 512-thread 128x128 tile, fused epilogue
    gemm_out_kernel<<<dim3(8, 32), 512, 0, stream>>>(attn, woT, bo, gamma, out);
}